// Round 9
// baseline (507.630 us; speedup 1.0000x reference)
//
#include <hip/hip_runtime.h>
#include <stdint.h>

#define NN 15000
#define NE 60000

typedef unsigned short u16;
typedef __attribute__((ext_vector_type(8))) short short8;
typedef __attribute__((ext_vector_type(4))) float f32x4;

// workspace layout (bytes)
#define XF_OFF    0u          // xf   : 15000*64*2 = 1,920,000
#define W2T_OFF   1920000u    // w2t  : 65*4096*2  =   532,480
#define ROOTT_OFF 2452480u    // rootT: 64*64*2    =     8,192
#define WCATT_OFF 2460672u    // wcatT: 240*64*2   =    30,720
#define SUMS_OFF  2491392u    // sums+cnt: 15000*65*4 = 3,900,000
#define HT_OFF    6391392u    // hT   : 64*60000*2 = 7,680,000  -> end 14,071,392

__device__ __forceinline__ unsigned cvtpk(float lo, float hi) {
    unsigned r;
    asm("v_cvt_pk_bf16_f32 %0, %1, %2" : "=v"(r) : "v"(lo), "v"(hi));
    return r;
}
__device__ __forceinline__ u16 f2b(float f) { return (u16)(cvtpk(f, f) & 0xffffu); }

// =============== K1: fused {h->hT, xf, weight-prep, zero} ===============
// block ranges: [0,469) h | [469,1407) xf | [1407,2523) prep | [2523,3476) zero
__global__ __launch_bounds__(256) void k_pre(
        const float* __restrict__ x,
        const int* __restrict__ inp, const int* __restrict__ outp,
        const int* __restrict__ ent, const int* __restrict__ enp,
        const float* __restrict__ esc,
        const float* __restrict__ in_emb, const float* __restrict__ out_emb,
        const float* __restrict__ nt_emb, const float* __restrict__ np_emb,
        const float* __restrict__ w1, const float* __restrict__ b1,
        const float* __restrict__ w2, const float* __restrict__ b2,
        const float* __restrict__ rootw,
        const float* __restrict__ wsup, const float* __restrict__ wnt,
        const float* __restrict__ wtg, const float* __restrict__ wpr,
        u16* __restrict__ xf, u16* __restrict__ w2t,
        u16* __restrict__ rootT, u16* __restrict__ wcatT,
        u16* __restrict__ hT, float4* __restrict__ zbase) {
    const int bid = blockIdx.x, tid = threadIdx.x;
    if (bid < 469) {
        // ---- h = relu(ea @ w1 + b1), written TRANSPOSED: hT[k][e] ----
        __shared__ float w1f[33 * 64];
        __shared__ float b1f[64];
        __shared__ float ea[128][34];
        const int e0 = bid * 128;
        for (int i = tid; i < 33 * 64; i += 256) w1f[i] = w1[i];
        if (tid < 64) b1f[tid] = b1[tid];
        for (int idx = tid; idx < 128 * 33; idx += 256) {
            int le = idx / 33, f = idx - le * 33;
            int e = e0 + le;
            float v = 0.f;
            if (e < NE) {
                if (f < 16)      v = nt_emb[ent[e] * 16 + f];
                else if (f < 32) v = np_emb[enp[e] * 16 + (f - 16)];
                else             v = esc[e];
            }
            ea[le][f] = v;
        }
        __syncthreads();
        const int c = tid & 63, eg = tid >> 6;  // c = hidden unit (k), eg = 32-edge run
        unsigned pk[16];
        #pragma unroll
        for (int l = 0; l < 32; l += 2) {
            float a0 = b1f[c], a1 = b1f[c];
            #pragma unroll
            for (int i = 0; i < 33; ++i) {
                a0 += ea[eg * 32 + l][i] * w1f[i * 64 + c];
                a1 += ea[eg * 32 + l + 1][i] * w1f[i * 64 + c];
            }
            pk[l >> 1] = cvtpk(fmaxf(a0, 0.f), fmaxf(a1, 0.f));
        }
        const int ew = e0 + eg * 32;
        if (ew + 32 <= NE) {                 // block 468/eg=3 (e>=60000) skipped
            uint4* dst = (uint4*)(hT + (size_t)c * NE + ew);
            #pragma unroll
            for (int q = 0; q < 4; ++q)
                dst[q] = make_uint4(pk[q * 4], pk[q * 4 + 1], pk[q * 4 + 2], pk[q * 4 + 3]);
        }
    } else if (bid < 1407) {
        // ---- xf = bf16(concat(x, in_emb[inp], out_emb[outp])) ----
        int t = (bid - 469) * 256 + tid;
        if (t >= NN * 16) return;
        int n = t >> 4, j4 = t & 15;
        float4 v;
        if (j4 < 8)       v = *(const float4*)(x + n * 32 + j4 * 4);
        else if (j4 < 12) v = *(const float4*)(in_emb + inp[n] * 16 + (j4 - 8) * 4);
        else              v = *(const float4*)(out_emb + outp[n] * 16 + (j4 - 12) * 4);
        uint2 p;
        p.x = cvtpk(v.x, v.y);
        p.y = cvtpk(v.z, v.w);
        *(uint2*)(xf + n * 64 + j4 * 4) = p;
    } else if (bid < 2523) {
        // ---- weight re-layouts ----
        int idx = (bid - 1407) * 256 + tid;
        if (idx < 65 * 4096) {
            int k = idx >> 12, r = idx & 4095, o = r >> 6, i = r & 63;
            float v = (k < 64) ? w2[(k << 12) + (i << 6) + o] : b2[(i << 6) + o];
            w2t[idx] = f2b(v);
        } else if (idx < 65 * 4096 + 4096) {
            int t = idx - 65 * 4096; int c = t >> 6, i = t & 63;
            rootT[t] = f2b(rootw[i * 64 + c]);
        } else if (idx < 65 * 4096 + 4096 + 15360) {
            int t = idx - (65 * 4096 + 4096); int col = t >> 6, k = t & 63;
            float v;
            if (col < 16)       v = wsup[k * 16 + col];
            else if (col < 48)  v = wnt[k * 32 + col - 16];
            else if (col < 112) v = wtg[k * 64 + col - 48];
            else                v = wpr[k * 128 + col - 112];
            wcatT[t] = f2b(v);
        }
    } else {
        // ---- zero sums+cnt ----
        int i = (bid - 2523) * 256 + tid;
        if (i < (NN * 65) / 4) zbase[i] = make_float4(0.f, 0.f, 0.f, 0.f);
    }
}

// =============== K2: fused msg GEMM + scatter-add (o-partitioned, LDS-persistent B) ===============
// msg[e,o] = sum_k h[e,k]*q_k[e,o] + bias-slice,  q_k[e,o] = sum_i g[e,i]*w2t[k][o][i]
// grid 256 = 4 o-quarters x 64; block = 512 thr = 8 waves, persistent (2 waves/SIMD, 1 block/CU).
// Block stages ALL 65 slices' 16-col portions in LDS (65 x 2KB = 130KB, XOR-swizzled — the
// round-4-verified 0-conflict pattern), one barrier, then each wave sweeps 64-edge tiles.
// Atomics: exactly ONCE per (edge, col) = 15.4MB total (round-8 lesson: atomics are HBM-level;
// 8x k-partials cost 280MB -> atomic-bound at 1.4TB/s). No launch_bounds reg cap (rounds 5/7).
__global__ __launch_bounds__(512) void k_msg(const int* __restrict__ ei,
                                             const u16* __restrict__ xf,
                                             const u16* __restrict__ hT,
                                             const u16* __restrict__ w2t,
                                             float* __restrict__ sums,
                                             float* __restrict__ cnt) {
    __shared__ __align__(16) char smem[65 * 2048];   // 133,120 B
    const int tid  = threadIdx.x;
    const int lane = tid & 63;
    const int wave = tid >> 6;
    const int lhi  = lane >> 4;
    const int llo  = lane & 15;
    const int oq   = blockIdx.x & 3;                 // 16-col quarter
    const int wslot = (blockIdx.x >> 2) * 8 + wave;  // 0..511 within this oq

    // ---- one-time LDS fill: this oq's 2KB portion of each of the 65 slices ----
    for (int sl = wave; sl < 65; sl += 8) {
        const char* src = (const char*)w2t + (size_t)sl * 8192 + oq * 2048;
        char* dst = smem + sl * 2048;
        #pragma unroll
        for (int it = 0; it < 2; ++it) {
            int lin = (lane + it * 64) * 16;
            int phys = lin ^ (((lin >> 7) & 7) << 4);
            *(uint4*)(dst + phys) = *(const uint4*)(src + lin);
        }
    }
    __syncthreads();   // only barrier in the kernel

    const int pc0 = (llo * 128 + lhi * 16) ^ ((llo & 7) << 4);
    const int pc1 = (llo * 128 + 64 + lhi * 16) ^ ((llo & 7) << 4);

    for (int t = wslot; t < 938; t += 512) {
        const int base = t * 64;
        short8 a[4][2]; int eb[4]; int4 d4[4];
        #pragma unroll
        for (int st = 0; st < 4; ++st) {
            int e = base + st * 16 + llo;
            int src = ei[e < NE ? e : NE - 1];
            a[st][0] = *(const short8*)(xf + (size_t)src * 64 + lhi * 8);
            a[st][1] = *(const short8*)(xf + (size_t)src * 64 + 32 + lhi * 8);
            int e2 = base + st * 16 + lhi * 4;
            eb[st] = (e2 > NE - 4) ? (NE - 4) : e2;
            d4[st] = *(const int4*)(ei + NE + eb[st]);
        }
        f32x4 acc[4];
        #pragma unroll
        for (int st = 0; st < 4; ++st) acc[st] = (f32x4){0.f, 0.f, 0.f, 0.f};

        uint2 hA[4], hB[4];
        #pragma unroll
        for (int st = 0; st < 4; ++st) hA[st] = *(const uint2*)(hT + eb[st]);  // k=0

        #pragma unroll
        for (int s = 0; s < 64; s += 2) {
            // prefetch h for slice s+1
            #pragma unroll
            for (int st = 0; st < 4; ++st)
                hB[st] = *(const uint2*)(hT + (size_t)(s + 1) * NE + eb[st]);
            {   // slice s (h in hA)
                const char* bb = smem + s * 2048;
                short8 B0 = *(const short8*)(bb + pc0);
                short8 B1 = *(const short8*)(bb + pc1);
                #pragma unroll
                for (int st = 0; st < 4; ++st) {
                    f32x4 q;
                    q = __builtin_amdgcn_mfma_f32_16x16x32_bf16(a[st][0], B0, (f32x4){0.f,0.f,0.f,0.f}, 0, 0, 0);
                    q = __builtin_amdgcn_mfma_f32_16x16x32_bf16(a[st][1], B1, q, 0, 0, 0);
                    union { unsigned u; float f; } u0, u1, u2, u3;
                    u0.u = hA[st].x << 16;         u1.u = hA[st].x & 0xffff0000u;
                    u2.u = hA[st].y << 16;         u3.u = hA[st].y & 0xffff0000u;
                    acc[st][0] = fmaf(u0.f, q[0], acc[st][0]);
                    acc[st][1] = fmaf(u1.f, q[1], acc[st][1]);
                    acc[st][2] = fmaf(u2.f, q[2], acc[st][2]);
                    acc[st][3] = fmaf(u3.f, q[3], acc[st][3]);
                }
            }
            // prefetch h for slice s+2
            if (s + 2 < 64) {
                #pragma unroll
                for (int st = 0; st < 4; ++st)
                    hA[st] = *(const uint2*)(hT + (size_t)(s + 2) * NE + eb[st]);
            }
            {   // slice s+1 (h in hB)
                const char* bb = smem + (s + 1) * 2048;
                short8 B0 = *(const short8*)(bb + pc0);
                short8 B1 = *(const short8*)(bb + pc1);
                #pragma unroll
                for (int st = 0; st < 4; ++st) {
                    f32x4 q;
                    q = __builtin_amdgcn_mfma_f32_16x16x32_bf16(a[st][0], B0, (f32x4){0.f,0.f,0.f,0.f}, 0, 0, 0);
                    q = __builtin_amdgcn_mfma_f32_16x16x32_bf16(a[st][1], B1, q, 0, 0, 0);
                    union { unsigned u; float f; } u0, u1, u2, u3;
                    u0.u = hB[st].x << 16;         u1.u = hB[st].x & 0xffff0000u;
                    u2.u = hB[st].y << 16;         u3.u = hB[st].y & 0xffff0000u;
                    acc[st][0] = fmaf(u0.f, q[0], acc[st][0]);
                    acc[st][1] = fmaf(u1.f, q[1], acc[st][1]);
                    acc[st][2] = fmaf(u2.f, q[2], acc[st][2]);
                    acc[st][3] = fmaf(u3.f, q[3], acc[st][3]);
                }
            }
        }
        {   // bias slice (LDS idx 64, h==1): MFMA straight into acc
            const char* bb = smem + 64 * 2048;
            short8 B0 = *(const short8*)(bb + pc0);
            short8 B1 = *(const short8*)(bb + pc1);
            #pragma unroll
            for (int st = 0; st < 4; ++st) {
                acc[st] = __builtin_amdgcn_mfma_f32_16x16x32_bf16(a[st][0], B0, acc[st], 0, 0, 0);
                acc[st] = __builtin_amdgcn_mfma_f32_16x16x32_bf16(a[st][1], B1, acc[st], 0, 0, 0);
            }
        }
        // scatter-add (C/D layout: col = oq*16+llo, row = lhi*4+r); oq0 also counts in-degree
        #pragma unroll
        for (int st = 0; st < 4; ++st) {
            #pragma unroll
            for (int r = 0; r < 4; ++r) {
                int e = base + st * 16 + lhi * 4 + r;
                if (e < NE) {
                    int d = (r == 0) ? d4[st].x : (r == 1) ? d4[st].y : (r == 2) ? d4[st].z : d4[st].w;
                    atomicAdd(sums + (size_t)d * 64 + oq * 16 + llo, acc[st][r]);
                    if (oq == 0 && llo == 0) atomicAdd(cnt + d, 1.0f);
                }
            }
        }
    }
}

// =============== K3: out = relu(aggr + xf@rootw + b); 4 heads (f32 out) ===============
__global__ __launch_bounds__(256) void k_out(const u16* __restrict__ xf,
                                             const float* __restrict__ sums,
                                             const float* __restrict__ cnt,
                                             const u16* __restrict__ rootT,
                                             const u16* __restrict__ wcatT,
                                             const float* __restrict__ convb,
                                             const float* __restrict__ bsup,
                                             const float* __restrict__ bnt,
                                             const float* __restrict__ btg,
                                             const float* __restrict__ bpr,
                                             float* __restrict__ outp) {
    __shared__ __align__(16) u16 outlds[4][16][72];
    int tid = threadIdx.x;
    int wave = tid >> 6, lane = tid & 63;
    int lhi = lane >> 4, llo = lane & 15;
    int sid = blockIdx.x * 4 + wave;
    const bool live = (sid < 938);
    if (!live) sid = 937;
    int n0 = sid * 16;

    short8 a1[2];
    #pragma unroll
    for (int c = 0; c < 2; ++c) {
        int node = n0 + llo; if (node >= NN) node = NN - 1;
        a1[c] = *(const short8*)(xf + (size_t)node * 64 + c * 32 + lhi * 8);
    }
    f32x4 racc[4];
    #pragma unroll
    for (int o = 0; o < 4; ++o) racc[o] = (f32x4){0.f, 0.f, 0.f, 0.f};
    #pragma unroll
    for (int c = 0; c < 2; ++c)
        #pragma unroll
        for (int o = 0; o < 4; ++o) {
            short8 b = *(const short8*)(rootT + (o * 16 + llo) * 64 + c * 32 + lhi * 8);
            racc[o] = __builtin_amdgcn_mfma_f32_16x16x32_bf16(a1[c], b, racc[o], 0, 0, 0);
        }
    #pragma unroll
    for (int o = 0; o < 4; ++o) {
        int col = o * 16 + llo;
        #pragma unroll
        for (int r = 0; r < 4; ++r) {
            int node = n0 + lhi * 4 + r;
            float v = 0.f;
            if (node < NN) v = sums[(size_t)node * 64 + col] / fmaxf(cnt[node], 1.0f);
            v += racc[o][r] + convb[col];
            v = fmaxf(v, 0.f);
            outlds[wave][lhi * 4 + r][col] = f2b(v);
        }
    }
    __syncthreads();
    short8 a2[2];
    #pragma unroll
    for (int c = 0; c < 2; ++c)
        a2[c] = *(const short8*)(&outlds[wave][llo][c * 32 + lhi * 8]);
    #pragma unroll
    for (int o = 0; o < 15; ++o) {
        f32x4 hacc = (f32x4){0.f, 0.f, 0.f, 0.f};
        #pragma unroll
        for (int c = 0; c < 2; ++c) {
            short8 b = *(const short8*)(wcatT + (o * 16 + llo) * 64 + c * 32 + lhi * 8);
            hacc = __builtin_amdgcn_mfma_f32_16x16x32_bf16(a2[c], b, hacc, 0, 0, 0);
        }
        int col = o * 16 + llo;
        float bv; size_t off0; int w_, csh;
        if (col < 16)       { bv = bsup[col];       off0 = 0;                 w_ = 16;  csh = 0;   }
        else if (col < 48)  { bv = bnt[col - 16];   off0 = (size_t)NN * 16;   w_ = 32;  csh = 16;  }
        else if (col < 112) { bv = btg[col - 48];   off0 = (size_t)NN * 48;   w_ = 64;  csh = 48;  }
        else                { bv = bpr[col - 112];  off0 = (size_t)NN * 112;  w_ = 128; csh = 112; }
        #pragma unroll
        for (int r = 0; r < 4; ++r) {
            int node = n0 + lhi * 4 + r;
            if (live && node < NN)
                outp[off0 + (size_t)node * w_ + (col - csh)] = hacc[r] + bv;
        }
    }
}

extern "C" void kernel_launch(void* const* d_in, const int* in_sizes, int n_in,
                              void* d_out, int out_size, void* d_ws, size_t ws_size,
                              hipStream_t stream) {
    const float* x        = (const float*)d_in[0];
    const int* input_np   = (const int*)d_in[1];
    const int* output_np  = (const int*)d_in[2];
    const int* edge_idx   = (const int*)d_in[3];
    const int* edge_nt    = (const int*)d_in[4];
    const int* edge_np    = (const int*)d_in[5];
    const float* edge_sc  = (const float*)d_in[6];
    const float* in_emb   = (const float*)d_in[7];
    const float* out_emb  = (const float*)d_in[8];
    const float* enp_emb  = (const float*)d_in[9];
    const float* ent_emb  = (const float*)d_in[10];
    const float* w1       = (const float*)d_in[11];
    const float* b1       = (const float*)d_in[12];
    const float* w2       = (const float*)d_in[13];
    const float* b2       = (const float*)d_in[14];
    const float* rootw    = (const float*)d_in[15];
    const float* convb    = (const float*)d_in[16];
    const float* wsup     = (const float*)d_in[17];
    const float* bsup     = (const float*)d_in[18];
    const float* wnt      = (const float*)d_in[19];
    const float* bnt      = (const float*)d_in[20];
    const float* wtg      = (const float*)d_in[21];
    const float* btg      = (const float*)d_in[22];
    const float* wpr      = (const float*)d_in[23];
    const float* bpr      = (const float*)d_in[24];

    char* ws = (char*)d_ws;
    u16* xf    = (u16*)(ws + XF_OFF);
    u16* w2t   = (u16*)(ws + W2T_OFF);
    u16* rootT = (u16*)(ws + ROOTT_OFF);
    u16* wcatT = (u16*)(ws + WCATT_OFF);
    float* sums = (float*)(ws + SUMS_OFF);
    float* cnt  = sums + (size_t)NN * 64;
    u16* hT    = (u16*)(ws + HT_OFF);

    k_pre<<<3476, 256, 0, stream>>>(x, input_np, output_np, edge_nt, edge_np, edge_sc,
                                    in_emb, out_emb, ent_emb, enp_emb, w1, b1, w2, b2,
                                    rootw, wsup, wnt, wtg, wpr,
                                    xf, w2t, rootT, wcatT, hT, (float4*)sums);
    k_msg<<<256, 512, 0, stream>>>(edge_idx, xf, hT, w2t, sums, cnt);
    k_out<<<235, 256, 0, stream>>>(xf, sums, cnt, rootT, wcatT, convb, bsup, bnt, btg, bpr, (float*)d_out);
}

// Round 10
// 502.793 us; speedup vs baseline: 1.0096x; 1.0096x over previous
//
#include <hip/hip_runtime.h>
#include <stdint.h>

#define NN 15000
#define NE 60000

typedef unsigned short u16;
typedef __attribute__((ext_vector_type(8))) short short8;
typedef __attribute__((ext_vector_type(4))) float f32x4;

// workspace layout (bytes)
#define XF_OFF    0u          // xf   : 15000*64*2 = 1,920,000
#define W2T_OFF   1920000u    // w2t  : 65*4096*2  =   532,480
#define ROOTT_OFF 2452480u    // rootT: 64*64*2    =     8,192
#define WCATT_OFF 2460672u    // wcatT: 240*64*2   =    30,720
#define SUMS_OFF  2491392u    // sums+cnt: 15000*65*4 = 3,900,000
#define HT_OFF    6391392u    // hT   : 64*60000*2 = 7,680,000  -> end 14,071,392

__device__ __forceinline__ unsigned cvtpk(float lo, float hi) {
    unsigned r;
    asm("v_cvt_pk_bf16_f32 %0, %1, %2" : "=v"(r) : "v"(lo), "v"(hi));
    return r;
}
__device__ __forceinline__ u16 f2b(float f) { return (u16)(cvtpk(f, f) & 0xffffu); }

// =============== K1: fused {h->hT, xf, weight-prep, zero} ===============
// block ranges: [0,469) h | [469,1407) xf | [1407,2523) prep | [2523,3476) zero
__global__ __launch_bounds__(256) void k_pre(
        const float* __restrict__ x,
        const int* __restrict__ inp, const int* __restrict__ outp,
        const int* __restrict__ ent, const int* __restrict__ enp,
        const float* __restrict__ esc,
        const float* __restrict__ in_emb, const float* __restrict__ out_emb,
        const float* __restrict__ nt_emb, const float* __restrict__ np_emb,
        const float* __restrict__ w1, const float* __restrict__ b1,
        const float* __restrict__ w2, const float* __restrict__ b2,
        const float* __restrict__ rootw,
        const float* __restrict__ wsup, const float* __restrict__ wnt,
        const float* __restrict__ wtg, const float* __restrict__ wpr,
        u16* __restrict__ xf, u16* __restrict__ w2t,
        u16* __restrict__ rootT, u16* __restrict__ wcatT,
        u16* __restrict__ hT, float4* __restrict__ zbase) {
    const int bid = blockIdx.x, tid = threadIdx.x;
    if (bid < 469) {
        // ---- h = relu(ea @ w1 + b1), written TRANSPOSED: hT[k][e] ----
        __shared__ float w1f[33 * 64];
        __shared__ float b1f[64];
        __shared__ float ea[128][34];
        const int e0 = bid * 128;
        for (int i = tid; i < 33 * 64; i += 256) w1f[i] = w1[i];
        if (tid < 64) b1f[tid] = b1[tid];
        for (int idx = tid; idx < 128 * 33; idx += 256) {
            int le = idx / 33, f = idx - le * 33;
            int e = e0 + le;
            float v = 0.f;
            if (e < NE) {
                if (f < 16)      v = nt_emb[ent[e] * 16 + f];
                else if (f < 32) v = np_emb[enp[e] * 16 + (f - 16)];
                else             v = esc[e];
            }
            ea[le][f] = v;
        }
        __syncthreads();
        const int c = tid & 63, eg = tid >> 6;  // c = hidden unit (k), eg = 32-edge run
        unsigned pk[16];
        #pragma unroll
        for (int l = 0; l < 32; l += 2) {
            float a0 = b1f[c], a1 = b1f[c];
            #pragma unroll
            for (int i = 0; i < 33; ++i) {
                a0 += ea[eg * 32 + l][i] * w1f[i * 64 + c];
                a1 += ea[eg * 32 + l + 1][i] * w1f[i * 64 + c];
            }
            pk[l >> 1] = cvtpk(fmaxf(a0, 0.f), fmaxf(a1, 0.f));
        }
        const int ew = e0 + eg * 32;
        if (ew + 32 <= NE) {                 // block 468/eg=3 (e>=60000) skipped
            uint4* dst = (uint4*)(hT + (size_t)c * NE + ew);
            #pragma unroll
            for (int q = 0; q < 4; ++q)
                dst[q] = make_uint4(pk[q * 4], pk[q * 4 + 1], pk[q * 4 + 2], pk[q * 4 + 3]);
        }
    } else if (bid < 1407) {
        // ---- xf = bf16(concat(x, in_emb[inp], out_emb[outp])) ----
        int t = (bid - 469) * 256 + tid;
        if (t >= NN * 16) return;
        int n = t >> 4, j4 = t & 15;
        float4 v;
        if (j4 < 8)       v = *(const float4*)(x + n * 32 + j4 * 4);
        else if (j4 < 12) v = *(const float4*)(in_emb + inp[n] * 16 + (j4 - 8) * 4);
        else              v = *(const float4*)(out_emb + outp[n] * 16 + (j4 - 12) * 4);
        uint2 p;
        p.x = cvtpk(v.x, v.y);
        p.y = cvtpk(v.z, v.w);
        *(uint2*)(xf + n * 64 + j4 * 4) = p;
    } else if (bid < 2523) {
        // ---- weight re-layouts ----
        int idx = (bid - 1407) * 256 + tid;
        if (idx < 65 * 4096) {
            int k = idx >> 12, r = idx & 4095, o = r >> 6, i = r & 63;
            float v = (k < 64) ? w2[(k << 12) + (i << 6) + o] : b2[(i << 6) + o];
            w2t[idx] = f2b(v);
        } else if (idx < 65 * 4096 + 4096) {
            int t = idx - 65 * 4096; int c = t >> 6, i = t & 63;
            rootT[t] = f2b(rootw[i * 64 + c]);
        } else if (idx < 65 * 4096 + 4096 + 15360) {
            int t = idx - (65 * 4096 + 4096); int col = t >> 6, k = t & 63;
            float v;
            if (col < 16)       v = wsup[k * 16 + col];
            else if (col < 48)  v = wnt[k * 32 + col - 16];
            else if (col < 112) v = wtg[k * 64 + col - 48];
            else                v = wpr[k * 128 + col - 112];
            wcatT[t] = f2b(v);
        }
    } else {
        // ---- zero sums+cnt ----
        int i = (bid - 2523) * 256 + tid;
        if (i < (NN * 65) / 4) zbase[i] = make_float4(0.f, 0.f, 0.f, 0.f);
    }
}

// =============== K2: fused msg GEMM + scatter-add (o-partitioned, LDS-persistent B) ===============
// msg[e,o] = sum_k h[e,k]*q_k[e,o] + bias-slice,  q_k[e,o] = sum_i g[e,i]*w2t[k][o][i]
// grid 256 = 4 o-quarters x 64; block = 512 thr = 8 waves, persistent (2 waves/SIMD via LDS).
// REGISTER LAW (rounds 5/7/9): hipcc VGPR cap = 256 / launch_bounds_2nd_arg; bare (512) defaults
// to w=2 -> cap 128 -> spilled 770MB scratch. Use (512,1) -> cap 256. Loop-carried state also
// trimmed (~85 regs: a 32, acc 16, h-dbuf 16, eb 4) by loading dst indices only in the epilogue.
__global__ __launch_bounds__(512, 1) void k_msg(const int* __restrict__ ei,
                                                const u16* __restrict__ xf,
                                                const u16* __restrict__ hT,
                                                const u16* __restrict__ w2t,
                                                float* __restrict__ sums,
                                                float* __restrict__ cnt) {
    __shared__ __align__(16) char smem[65 * 2048];   // 133,120 B
    const int tid  = threadIdx.x;
    const int lane = tid & 63;
    const int wave = tid >> 6;
    const int lhi  = lane >> 4;
    const int llo  = lane & 15;
    const int oq   = blockIdx.x & 3;                 // 16-col quarter
    const int wslot = (blockIdx.x >> 2) * 8 + wave;  // 0..511 within this oq

    // ---- one-time LDS fill: this oq's 2KB portion of each of the 65 slices ----
    for (int sl = wave; sl < 65; sl += 8) {
        const char* src = (const char*)w2t + (size_t)sl * 8192 + oq * 2048;
        char* dst = smem + sl * 2048;
        #pragma unroll
        for (int it = 0; it < 2; ++it) {
            int lin = (lane + it * 64) * 16;
            int phys = lin ^ (((lin >> 7) & 7) << 4);
            *(uint4*)(dst + phys) = *(const uint4*)(src + lin);
        }
    }
    __syncthreads();   // only barrier in the kernel

    const int pc0 = (llo * 128 + lhi * 16) ^ ((llo & 7) << 4);
    const int pc1 = (llo * 128 + 64 + lhi * 16) ^ ((llo & 7) << 4);

    for (int t = wslot; t < 938; t += 512) {
        const int base = t * 64;
        short8 a[4][2]; int eb[4];
        #pragma unroll
        for (int st = 0; st < 4; ++st) {
            int e = base + st * 16 + llo;
            int src = ei[e < NE ? e : NE - 1];
            a[st][0] = *(const short8*)(xf + (size_t)src * 64 + lhi * 8);
            a[st][1] = *(const short8*)(xf + (size_t)src * 64 + 32 + lhi * 8);
            int e2 = base + st * 16 + lhi * 4;
            eb[st] = (e2 > NE - 4) ? (NE - 4) : e2;
        }
        f32x4 acc[4];
        #pragma unroll
        for (int st = 0; st < 4; ++st) acc[st] = (f32x4){0.f, 0.f, 0.f, 0.f};

        uint2 hA[4], hB[4];
        #pragma unroll
        for (int st = 0; st < 4; ++st) hA[st] = *(const uint2*)(hT + eb[st]);  // k=0

        #pragma unroll
        for (int s = 0; s < 64; s += 2) {
            // prefetch h for slice s+1
            #pragma unroll
            for (int st = 0; st < 4; ++st)
                hB[st] = *(const uint2*)(hT + (size_t)(s + 1) * NE + eb[st]);
            {   // slice s (h in hA)
                const char* bb = smem + s * 2048;
                short8 B0 = *(const short8*)(bb + pc0);
                short8 B1 = *(const short8*)(bb + pc1);
                #pragma unroll
                for (int st = 0; st < 4; ++st) {
                    f32x4 q;
                    q = __builtin_amdgcn_mfma_f32_16x16x32_bf16(a[st][0], B0, (f32x4){0.f,0.f,0.f,0.f}, 0, 0, 0);
                    q = __builtin_amdgcn_mfma_f32_16x16x32_bf16(a[st][1], B1, q, 0, 0, 0);
                    union { unsigned u; float f; } u0, u1, u2, u3;
                    u0.u = hA[st].x << 16;         u1.u = hA[st].x & 0xffff0000u;
                    u2.u = hA[st].y << 16;         u3.u = hA[st].y & 0xffff0000u;
                    acc[st][0] = fmaf(u0.f, q[0], acc[st][0]);
                    acc[st][1] = fmaf(u1.f, q[1], acc[st][1]);
                    acc[st][2] = fmaf(u2.f, q[2], acc[st][2]);
                    acc[st][3] = fmaf(u3.f, q[3], acc[st][3]);
                }
            }
            // prefetch h for slice s+2
            if (s + 2 < 64) {
                #pragma unroll
                for (int st = 0; st < 4; ++st)
                    hA[st] = *(const uint2*)(hT + (size_t)(s + 2) * NE + eb[st]);
            }
            {   // slice s+1 (h in hB)
                const char* bb = smem + (s + 1) * 2048;
                short8 B0 = *(const short8*)(bb + pc0);
                short8 B1 = *(const short8*)(bb + pc1);
                #pragma unroll
                for (int st = 0; st < 4; ++st) {
                    f32x4 q;
                    q = __builtin_amdgcn_mfma_f32_16x16x32_bf16(a[st][0], B0, (f32x4){0.f,0.f,0.f,0.f}, 0, 0, 0);
                    q = __builtin_amdgcn_mfma_f32_16x16x32_bf16(a[st][1], B1, q, 0, 0, 0);
                    union { unsigned u; float f; } u0, u1, u2, u3;
                    u0.u = hB[st].x << 16;         u1.u = hB[st].x & 0xffff0000u;
                    u2.u = hB[st].y << 16;         u3.u = hB[st].y & 0xffff0000u;
                    acc[st][0] = fmaf(u0.f, q[0], acc[st][0]);
                    acc[st][1] = fmaf(u1.f, q[1], acc[st][1]);
                    acc[st][2] = fmaf(u2.f, q[2], acc[st][2]);
                    acc[st][3] = fmaf(u3.f, q[3], acc[st][3]);
                }
            }
        }
        {   // bias slice (LDS idx 64, h==1): MFMA straight into acc
            const char* bb = smem + 64 * 2048;
            short8 B0 = *(const short8*)(bb + pc0);
            short8 B1 = *(const short8*)(bb + pc1);
            #pragma unroll
            for (int st = 0; st < 4; ++st) {
                acc[st] = __builtin_amdgcn_mfma_f32_16x16x32_bf16(a[st][0], B0, acc[st], 0, 0, 0);
                acc[st] = __builtin_amdgcn_mfma_f32_16x16x32_bf16(a[st][1], B1, acc[st], 0, 0, 0);
            }
        }
        // scatter-add (C/D layout: col = oq*16+llo, row = lhi*4+r); oq0 also counts in-degree.
        // dst indices loaded HERE (transient) — not loop-carried (round-9 spill lesson).
        #pragma unroll
        for (int st = 0; st < 4; ++st) {
            int4 d4 = *(const int4*)(ei + NE + eb[st]);
            #pragma unroll
            for (int r = 0; r < 4; ++r) {
                int e = base + st * 16 + lhi * 4 + r;
                if (e < NE) {
                    int d = (r == 0) ? d4.x : (r == 1) ? d4.y : (r == 2) ? d4.z : d4.w;
                    atomicAdd(sums + (size_t)d * 64 + oq * 16 + llo, acc[st][r]);
                    if (oq == 0 && llo == 0) atomicAdd(cnt + d, 1.0f);
                }
            }
        }
    }
}

// =============== K3: out = relu(aggr + xf@rootw + b); 4 heads (f32 out) ===============
__global__ __launch_bounds__(256) void k_out(const u16* __restrict__ xf,
                                             const float* __restrict__ sums,
                                             const float* __restrict__ cnt,
                                             const u16* __restrict__ rootT,
                                             const u16* __restrict__ wcatT,
                                             const float* __restrict__ convb,
                                             const float* __restrict__ bsup,
                                             const float* __restrict__ bnt,
                                             const float* __restrict__ btg,
                                             const float* __restrict__ bpr,
                                             float* __restrict__ outp) {
    __shared__ __align__(16) u16 outlds[4][16][72];
    int tid = threadIdx.x;
    int wave = tid >> 6, lane = tid & 63;
    int lhi = lane >> 4, llo = lane & 15;
    int sid = blockIdx.x * 4 + wave;
    const bool live = (sid < 938);
    if (!live) sid = 937;
    int n0 = sid * 16;

    short8 a1[2];
    #pragma unroll
    for (int c = 0; c < 2; ++c) {
        int node = n0 + llo; if (node >= NN) node = NN - 1;
        a1[c] = *(const short8*)(xf + (size_t)node * 64 + c * 32 + lhi * 8);
    }
    f32x4 racc[4];
    #pragma unroll
    for (int o = 0; o < 4; ++o) racc[o] = (f32x4){0.f, 0.f, 0.f, 0.f};
    #pragma unroll
    for (int c = 0; c < 2; ++c)
        #pragma unroll
        for (int o = 0; o < 4; ++o) {
            short8 b = *(const short8*)(rootT + (o * 16 + llo) * 64 + c * 32 + lhi * 8);
            racc[o] = __builtin_amdgcn_mfma_f32_16x16x32_bf16(a1[c], b, racc[o], 0, 0, 0);
        }
    #pragma unroll
    for (int o = 0; o < 4; ++o) {
        int col = o * 16 + llo;
        #pragma unroll
        for (int r = 0; r < 4; ++r) {
            int node = n0 + lhi * 4 + r;
            float v = 0.f;
            if (node < NN) v = sums[(size_t)node * 64 + col] / fmaxf(cnt[node], 1.0f);
            v += racc[o][r] + convb[col];
            v = fmaxf(v, 0.f);
            outlds[wave][lhi * 4 + r][col] = f2b(v);
        }
    }
    __syncthreads();
    short8 a2[2];
    #pragma unroll
    for (int c = 0; c < 2; ++c)
        a2[c] = *(const short8*)(&outlds[wave][llo][c * 32 + lhi * 8]);
    #pragma unroll
    for (int o = 0; o < 15; ++o) {
        f32x4 hacc = (f32x4){0.f, 0.f, 0.f, 0.f};
        #pragma unroll
        for (int c = 0; c < 2; ++c) {
            short8 b = *(const short8*)(wcatT + (o * 16 + llo) * 64 + c * 32 + lhi * 8);
            hacc = __builtin_amdgcn_mfma_f32_16x16x32_bf16(a2[c], b, hacc, 0, 0, 0);
        }
        int col = o * 16 + llo;
        float bv; size_t off0; int w_, csh;
        if (col < 16)       { bv = bsup[col];       off0 = 0;                 w_ = 16;  csh = 0;   }
        else if (col < 48)  { bv = bnt[col - 16];   off0 = (size_t)NN * 16;   w_ = 32;  csh = 16;  }
        else if (col < 112) { bv = btg[col - 48];   off0 = (size_t)NN * 48;   w_ = 64;  csh = 48;  }
        else                { bv = bpr[col - 112];  off0 = (size_t)NN * 112;  w_ = 128; csh = 112; }
        #pragma unroll
        for (int r = 0; r < 4; ++r) {
            int node = n0 + lhi * 4 + r;
            if (live && node < NN)
                outp[off0 + (size_t)node * w_ + (col - csh)] = hacc[r] + bv;
        }
    }
}

extern "C" void kernel_launch(void* const* d_in, const int* in_sizes, int n_in,
                              void* d_out, int out_size, void* d_ws, size_t ws_size,
                              hipStream_t stream) {
    const float* x        = (const float*)d_in[0];
    const int* input_np   = (const int*)d_in[1];
    const int* output_np  = (const int*)d_in[2];
    const int* edge_idx   = (const int*)d_in[3];
    const int* edge_nt    = (const int*)d_in[4];
    const int* edge_np    = (const int*)d_in[5];
    const float* edge_sc  = (const float*)d_in[6];
    const float* in_emb   = (const float*)d_in[7];
    const float* out_emb  = (const float*)d_in[8];
    const float* enp_emb  = (const float*)d_in[9];
    const float* ent_emb  = (const float*)d_in[10];
    const float* w1       = (const float*)d_in[11];
    const float* b1       = (const float*)d_in[12];
    const float* w2       = (const float*)d_in[13];
    const float* b2       = (const float*)d_in[14];
    const float* rootw    = (const float*)d_in[15];
    const float* convb    = (const float*)d_in[16];
    const float* wsup     = (const float*)d_in[17];
    const float* bsup     = (const float*)d_in[18];
    const float* wnt      = (const float*)d_in[19];
    const float* bnt      = (const float*)d_in[20];
    const float* wtg      = (const float*)d_in[21];
    const float* btg      = (const float*)d_in[22];
    const float* wpr      = (const float*)d_in[23];
    const float* bpr      = (const float*)d_in[24];

    char* ws = (char*)d_ws;
    u16* xf    = (u16*)(ws + XF_OFF);
    u16* w2t   = (u16*)(ws + W2T_OFF);
    u16* rootT = (u16*)(ws + ROOTT_OFF);
    u16* wcatT = (u16*)(ws + WCATT_OFF);
    float* sums = (float*)(ws + SUMS_OFF);
    float* cnt  = sums + (size_t)NN * 64;
    u16* hT    = (u16*)(ws + HT_OFF);

    k_pre<<<3476, 256, 0, stream>>>(x, input_np, output_np, edge_nt, edge_np, edge_sc,
                                    in_emb, out_emb, ent_emb, enp_emb, w1, b1, w2, b2,
                                    rootw, wsup, wnt, wtg, wpr,
                                    xf, w2t, rootT, wcatT, hT, (float4*)sums);
    k_msg<<<256, 512, 0, stream>>>(edge_idx, xf, hT, w2t, sums, cnt);
    k_out<<<235, 256, 0, stream>>>(xf, sums, cnt, rootT, wcatT, convb, bsup, bnt, btg, bpr, (float*)d_out);
}

// Round 11
// 107.506 us; speedup vs baseline: 4.7219x; 4.6769x over previous
//
#include <hip/hip_runtime.h>
#include <stdint.h>

#define NN 15000
#define NE 60000

typedef unsigned short u16;
typedef __attribute__((ext_vector_type(8))) short short8;
typedef __attribute__((ext_vector_type(4))) float f32x4;

// workspace layout (bytes)
#define XF_OFF    0u          // xf   : 15000*64*2 = 1,920,000
#define W2T_OFF   1920000u    // w2t  : 65*4096*2  =   532,480
#define ROOTT_OFF 2452480u    // rootT: 64*64*2    =     8,192
#define WCATT_OFF 2460672u    // wcatT: 240*64*2   =    30,720
#define SUMS_OFF  2491392u    // sums+cnt: 15000*65*4 = 3,900,000
#define HT_OFF    6391392u    // hT   : 64*60000*2 = 7,680,000  -> end 14,071,392

__device__ __forceinline__ unsigned cvtpk(float lo, float hi) {
    unsigned r;
    asm("v_cvt_pk_bf16_f32 %0, %1, %2" : "=v"(r) : "v"(lo), "v"(hi));
    return r;
}
__device__ __forceinline__ u16 f2b(float f) { return (u16)(cvtpk(f, f) & 0xffffu); }

// =============== K1: fused {h->hT, xf, weight-prep, zero} ===============
// block ranges: [0,469) h | [469,1407) xf | [1407,2523) prep | [2523,3476) zero
__global__ __launch_bounds__(256) void k_pre(
        const float* __restrict__ x,
        const int* __restrict__ inp, const int* __restrict__ outp,
        const int* __restrict__ ent, const int* __restrict__ enp,
        const float* __restrict__ esc,
        const float* __restrict__ in_emb, const float* __restrict__ out_emb,
        const float* __restrict__ nt_emb, const float* __restrict__ np_emb,
        const float* __restrict__ w1, const float* __restrict__ b1,
        const float* __restrict__ w2, const float* __restrict__ b2,
        const float* __restrict__ rootw,
        const float* __restrict__ wsup, const float* __restrict__ wnt,
        const float* __restrict__ wtg, const float* __restrict__ wpr,
        u16* __restrict__ xf, u16* __restrict__ w2t,
        u16* __restrict__ rootT, u16* __restrict__ wcatT,
        u16* __restrict__ hT, float4* __restrict__ zbase) {
    const int bid = blockIdx.x, tid = threadIdx.x;
    if (bid < 469) {
        // ---- h = relu(ea @ w1 + b1), written TRANSPOSED: hT[k][e] ----
        __shared__ float w1f[33 * 64];
        __shared__ float b1f[64];
        __shared__ float ea[128][34];
        const int e0 = bid * 128;
        for (int i = tid; i < 33 * 64; i += 256) w1f[i] = w1[i];
        if (tid < 64) b1f[tid] = b1[tid];
        for (int idx = tid; idx < 128 * 33; idx += 256) {
            int le = idx / 33, f = idx - le * 33;
            int e = e0 + le;
            float v = 0.f;
            if (e < NE) {
                if (f < 16)      v = nt_emb[ent[e] * 16 + f];
                else if (f < 32) v = np_emb[enp[e] * 16 + (f - 16)];
                else             v = esc[e];
            }
            ea[le][f] = v;
        }
        __syncthreads();
        const int c = tid & 63, eg = tid >> 6;  // c = hidden unit (k), eg = 32-edge run
        unsigned pk[16];
        #pragma unroll
        for (int l = 0; l < 32; l += 2) {
            float a0 = b1f[c], a1 = b1f[c];
            #pragma unroll
            for (int i = 0; i < 33; ++i) {
                a0 += ea[eg * 32 + l][i] * w1f[i * 64 + c];
                a1 += ea[eg * 32 + l + 1][i] * w1f[i * 64 + c];
            }
            pk[l >> 1] = cvtpk(fmaxf(a0, 0.f), fmaxf(a1, 0.f));
        }
        const int ew = e0 + eg * 32;
        if (ew + 32 <= NE) {                 // block 468/eg=3 (e>=60000) skipped
            uint4* dst = (uint4*)(hT + (size_t)c * NE + ew);
            #pragma unroll
            for (int q = 0; q < 4; ++q)
                dst[q] = make_uint4(pk[q * 4], pk[q * 4 + 1], pk[q * 4 + 2], pk[q * 4 + 3]);
        }
    } else if (bid < 1407) {
        // ---- xf = bf16(concat(x, in_emb[inp], out_emb[outp])) ----
        int t = (bid - 469) * 256 + tid;
        if (t >= NN * 16) return;
        int n = t >> 4, j4 = t & 15;
        float4 v;
        if (j4 < 8)       v = *(const float4*)(x + n * 32 + j4 * 4);
        else if (j4 < 12) v = *(const float4*)(in_emb + inp[n] * 16 + (j4 - 8) * 4);
        else              v = *(const float4*)(out_emb + outp[n] * 16 + (j4 - 12) * 4);
        uint2 p;
        p.x = cvtpk(v.x, v.y);
        p.y = cvtpk(v.z, v.w);
        *(uint2*)(xf + n * 64 + j4 * 4) = p;
    } else if (bid < 2523) {
        // ---- weight re-layouts ----
        int idx = (bid - 1407) * 256 + tid;
        if (idx < 65 * 4096) {
            int k = idx >> 12, r = idx & 4095, o = r >> 6, i = r & 63;
            float v = (k < 64) ? w2[(k << 12) + (i << 6) + o] : b2[(i << 6) + o];
            w2t[idx] = f2b(v);
        } else if (idx < 65 * 4096 + 4096) {
            int t = idx - 65 * 4096; int c = t >> 6, i = t & 63;
            rootT[t] = f2b(rootw[i * 64 + c]);
        } else if (idx < 65 * 4096 + 4096 + 15360) {
            int t = idx - (65 * 4096 + 4096); int col = t >> 6, k = t & 63;
            float v;
            if (col < 16)       v = wsup[k * 16 + col];
            else if (col < 48)  v = wnt[k * 32 + col - 16];
            else if (col < 112) v = wtg[k * 64 + col - 48];
            else                v = wpr[k * 128 + col - 112];
            wcatT[t] = f2b(v);
        }
    } else {
        // ---- zero sums+cnt ----
        int i = (bid - 2523) * 256 + tid;
        if (i < (NN * 65) / 4) zbase[i] = make_float4(0.f, 0.f, 0.f, 0.f);
    }
}

// =============== K2: fused msg GEMM + scatter-add (o-partitioned, LDS-persistent B) ===============
// msg[e,o] = sum_k h[e,k]*q_k[e,o] + bias-slice,  q_k[e,o] = sum_i g[e,i]*w2t[k][o][i]
// grid 236 = 4 o-quarters x 59; block = 512 thr = 8 waves, persistent (2 waves/SIMD via LDS).
// Each wave sweeps ~2 tiles (938 / 472 slots). Atomics exactly once per (edge,col).
// ROUND-10 LESSON: the slice loop was `#pragma unroll` (full, 32 iters) -> scheduler pipelined
// dozens of loads -> live ranges >> 128-reg cap -> 763MB scratch. The loop is now `unroll 1`
// with a manual 2-slice double-buffered body; loop state ~80 regs fits any cap.
__global__ __launch_bounds__(512, 1) void k_msg(const int* __restrict__ ei,
                                                const u16* __restrict__ xf,
                                                const u16* __restrict__ hT,
                                                const u16* __restrict__ w2t,
                                                float* __restrict__ sums,
                                                float* __restrict__ cnt) {
    __shared__ __align__(16) char smem[65 * 2048];   // 133,120 B
    const int tid  = threadIdx.x;
    const int lane = tid & 63;
    const int wave = tid >> 6;
    const int lhi  = lane >> 4;
    const int llo  = lane & 15;
    const int oq   = blockIdx.x & 3;                 // 16-col quarter
    const int wslot = (blockIdx.x >> 2) * 8 + wave;  // 0..471 within this oq

    // ---- one-time LDS fill: this oq's 2KB portion of each of the 65 slices ----
    for (int sl = wave; sl < 65; sl += 8) {
        const char* src = (const char*)w2t + (size_t)sl * 8192 + oq * 2048;
        char* dst = smem + sl * 2048;
        #pragma unroll
        for (int it = 0; it < 2; ++it) {
            int lin = (lane + it * 64) * 16;
            int phys = lin ^ (((lin >> 7) & 7) << 4);
            *(uint4*)(dst + phys) = *(const uint4*)(src + lin);
        }
    }
    __syncthreads();   // only barrier in the kernel

    const int pc0 = (llo * 128 + lhi * 16) ^ ((llo & 7) << 4);
    const int pc1 = (llo * 128 + 64 + lhi * 16) ^ ((llo & 7) << 4);

    for (int t = wslot; t < 938; t += 472) {
        const int base = t * 64;
        short8 a[4][2]; int eb[4];
        #pragma unroll
        for (int st = 0; st < 4; ++st) {
            int e = base + st * 16 + llo;
            int src = ei[e < NE ? e : NE - 1];
            a[st][0] = *(const short8*)(xf + (size_t)src * 64 + lhi * 8);
            a[st][1] = *(const short8*)(xf + (size_t)src * 64 + 32 + lhi * 8);
            int e2 = base + st * 16 + lhi * 4;
            eb[st] = (e2 > NE - 4) ? (NE - 4) : e2;
        }
        f32x4 acc[4];
        #pragma unroll
        for (int st = 0; st < 4; ++st) acc[st] = (f32x4){0.f, 0.f, 0.f, 0.f};

        uint2 hA[4], hB[4];
        #pragma unroll
        for (int st = 0; st < 4; ++st) hA[st] = *(const uint2*)(hT + eb[st]);  // k=0

        #pragma unroll 1   // CRITICAL: full unroll here caused the round-9/10 spill storm
        for (int s = 0; s < 64; s += 2) {
            // prefetch h for slice s+1
            #pragma unroll
            for (int st = 0; st < 4; ++st)
                hB[st] = *(const uint2*)(hT + (size_t)(s + 1) * NE + eb[st]);
            {   // slice s (h in hA)
                const char* bb = smem + s * 2048;
                short8 B0 = *(const short8*)(bb + pc0);
                short8 B1 = *(const short8*)(bb + pc1);
                #pragma unroll
                for (int st = 0; st < 4; ++st) {
                    f32x4 q;
                    q = __builtin_amdgcn_mfma_f32_16x16x32_bf16(a[st][0], B0, (f32x4){0.f,0.f,0.f,0.f}, 0, 0, 0);
                    q = __builtin_amdgcn_mfma_f32_16x16x32_bf16(a[st][1], B1, q, 0, 0, 0);
                    union { unsigned u; float f; } u0, u1, u2, u3;
                    u0.u = hA[st].x << 16;         u1.u = hA[st].x & 0xffff0000u;
                    u2.u = hA[st].y << 16;         u3.u = hA[st].y & 0xffff0000u;
                    acc[st][0] = fmaf(u0.f, q[0], acc[st][0]);
                    acc[st][1] = fmaf(u1.f, q[1], acc[st][1]);
                    acc[st][2] = fmaf(u2.f, q[2], acc[st][2]);
                    acc[st][3] = fmaf(u3.f, q[3], acc[st][3]);
                }
            }
            // prefetch h for slice s+2
            if (s + 2 < 64) {
                #pragma unroll
                for (int st = 0; st < 4; ++st)
                    hA[st] = *(const uint2*)(hT + (size_t)(s + 2) * NE + eb[st]);
            }
            {   // slice s+1 (h in hB)
                const char* bb = smem + (s + 1) * 2048;
                short8 B0 = *(const short8*)(bb + pc0);
                short8 B1 = *(const short8*)(bb + pc1);
                #pragma unroll
                for (int st = 0; st < 4; ++st) {
                    f32x4 q;
                    q = __builtin_amdgcn_mfma_f32_16x16x32_bf16(a[st][0], B0, (f32x4){0.f,0.f,0.f,0.f}, 0, 0, 0);
                    q = __builtin_amdgcn_mfma_f32_16x16x32_bf16(a[st][1], B1, q, 0, 0, 0);
                    union { unsigned u; float f; } u0, u1, u2, u3;
                    u0.u = hB[st].x << 16;         u1.u = hB[st].x & 0xffff0000u;
                    u2.u = hB[st].y << 16;         u3.u = hB[st].y & 0xffff0000u;
                    acc[st][0] = fmaf(u0.f, q[0], acc[st][0]);
                    acc[st][1] = fmaf(u1.f, q[1], acc[st][1]);
                    acc[st][2] = fmaf(u2.f, q[2], acc[st][2]);
                    acc[st][3] = fmaf(u3.f, q[3], acc[st][3]);
                }
            }
        }
        {   // bias slice (LDS idx 64, h==1): MFMA straight into acc
            const char* bb = smem + 64 * 2048;
            short8 B0 = *(const short8*)(bb + pc0);
            short8 B1 = *(const short8*)(bb + pc1);
            #pragma unroll
            for (int st = 0; st < 4; ++st) {
                acc[st] = __builtin_amdgcn_mfma_f32_16x16x32_bf16(a[st][0], B0, acc[st], 0, 0, 0);
                acc[st] = __builtin_amdgcn_mfma_f32_16x16x32_bf16(a[st][1], B1, acc[st], 0, 0, 0);
            }
        }
        // scatter-add (C/D layout: col = oq*16+llo, row = lhi*4+r); oq0 also counts in-degree.
        // dst indices loaded here (transient), not loop-carried.
        #pragma unroll
        for (int st = 0; st < 4; ++st) {
            int4 d4 = *(const int4*)(ei + NE + eb[st]);
            #pragma unroll
            for (int r = 0; r < 4; ++r) {
                int e = base + st * 16 + lhi * 4 + r;
                if (e < NE) {
                    int d = (r == 0) ? d4.x : (r == 1) ? d4.y : (r == 2) ? d4.z : d4.w;
                    atomicAdd(sums + (size_t)d * 64 + oq * 16 + llo, acc[st][r]);
                    if (oq == 0 && llo == 0) atomicAdd(cnt + d, 1.0f);
                }
            }
        }
    }
}

// =============== K3: out = relu(aggr + xf@rootw + b); 4 heads (f32 out) ===============
__global__ __launch_bounds__(256) void k_out(const u16* __restrict__ xf,
                                             const float* __restrict__ sums,
                                             const float* __restrict__ cnt,
                                             const u16* __restrict__ rootT,
                                             const u16* __restrict__ wcatT,
                                             const float* __restrict__ convb,
                                             const float* __restrict__ bsup,
                                             const float* __restrict__ bnt,
                                             const float* __restrict__ btg,
                                             const float* __restrict__ bpr,
                                             float* __restrict__ outp) {
    __shared__ __align__(16) u16 outlds[4][16][72];
    int tid = threadIdx.x;
    int wave = tid >> 6, lane = tid & 63;
    int lhi = lane >> 4, llo = lane & 15;
    int sid = blockIdx.x * 4 + wave;
    const bool live = (sid < 938);
    if (!live) sid = 937;
    int n0 = sid * 16;

    short8 a1[2];
    #pragma unroll
    for (int c = 0; c < 2; ++c) {
        int node = n0 + llo; if (node >= NN) node = NN - 1;
        a1[c] = *(const short8*)(xf + (size_t)node * 64 + c * 32 + lhi * 8);
    }
    f32x4 racc[4];
    #pragma unroll
    for (int o = 0; o < 4; ++o) racc[o] = (f32x4){0.f, 0.f, 0.f, 0.f};
    #pragma unroll
    for (int c = 0; c < 2; ++c)
        #pragma unroll
        for (int o = 0; o < 4; ++o) {
            short8 b = *(const short8*)(rootT + (o * 16 + llo) * 64 + c * 32 + lhi * 8);
            racc[o] = __builtin_amdgcn_mfma_f32_16x16x32_bf16(a1[c], b, racc[o], 0, 0, 0);
        }
    #pragma unroll
    for (int o = 0; o < 4; ++o) {
        int col = o * 16 + llo;
        #pragma unroll
        for (int r = 0; r < 4; ++r) {
            int node = n0 + lhi * 4 + r;
            float v = 0.f;
            if (node < NN) v = sums[(size_t)node * 64 + col] / fmaxf(cnt[node], 1.0f);
            v += racc[o][r] + convb[col];
            v = fmaxf(v, 0.f);
            outlds[wave][lhi * 4 + r][col] = f2b(v);
        }
    }
    __syncthreads();
    short8 a2[2];
    #pragma unroll
    for (int c = 0; c < 2; ++c)
        a2[c] = *(const short8*)(&outlds[wave][llo][c * 32 + lhi * 8]);
    #pragma unroll
    for (int o = 0; o < 15; ++o) {
        f32x4 hacc = (f32x4){0.f, 0.f, 0.f, 0.f};
        #pragma unroll
        for (int c = 0; c < 2; ++c) {
            short8 b = *(const short8*)(wcatT + (o * 16 + llo) * 64 + c * 32 + lhi * 8);
            hacc = __builtin_amdgcn_mfma_f32_16x16x32_bf16(a2[c], b, hacc, 0, 0, 0);
        }
        int col = o * 16 + llo;
        float bv; size_t off0; int w_, csh;
        if (col < 16)       { bv = bsup[col];       off0 = 0;                 w_ = 16;  csh = 0;   }
        else if (col < 48)  { bv = bnt[col - 16];   off0 = (size_t)NN * 16;   w_ = 32;  csh = 16;  }
        else if (col < 112) { bv = btg[col - 48];   off0 = (size_t)NN * 48;   w_ = 64;  csh = 48;  }
        else                { bv = bpr[col - 112];  off0 = (size_t)NN * 112;  w_ = 128; csh = 112; }
        #pragma unroll
        for (int r = 0; r < 4; ++r) {
            int node = n0 + lhi * 4 + r;
            if (live && node < NN)
                outp[off0 + (size_t)node * w_ + (col - csh)] = hacc[r] + bv;
        }
    }
}

extern "C" void kernel_launch(void* const* d_in, const int* in_sizes, int n_in,
                              void* d_out, int out_size, void* d_ws, size_t ws_size,
                              hipStream_t stream) {
    const float* x        = (const float*)d_in[0];
    const int* input_np   = (const int*)d_in[1];
    const int* output_np  = (const int*)d_in[2];
    const int* edge_idx   = (const int*)d_in[3];
    const int* edge_nt    = (const int*)d_in[4];
    const int* edge_np    = (const int*)d_in[5];
    const float* edge_sc  = (const float*)d_in[6];
    const float* in_emb   = (const float*)d_in[7];
    const float* out_emb  = (const float*)d_in[8];
    const float* enp_emb  = (const float*)d_in[9];
    const float* ent_emb  = (const float*)d_in[10];
    const float* w1       = (const float*)d_in[11];
    const float* b1       = (const float*)d_in[12];
    const float* w2       = (const float*)d_in[13];
    const float* b2       = (const float*)d_in[14];
    const float* rootw    = (const float*)d_in[15];
    const float* convb    = (const float*)d_in[16];
    const float* wsup     = (const float*)d_in[17];
    const float* bsup     = (const float*)d_in[18];
    const float* wnt      = (const float*)d_in[19];
    const float* bnt      = (const float*)d_in[20];
    const float* wtg      = (const float*)d_in[21];
    const float* btg      = (const float*)d_in[22];
    const float* wpr      = (const float*)d_in[23];
    const float* bpr      = (const float*)d_in[24];

    char* ws = (char*)d_ws;
    u16* xf    = (u16*)(ws + XF_OFF);
    u16* w2t   = (u16*)(ws + W2T_OFF);
    u16* rootT = (u16*)(ws + ROOTT_OFF);
    u16* wcatT = (u16*)(ws + WCATT_OFF);
    float* sums = (float*)(ws + SUMS_OFF);
    float* cnt  = sums + (size_t)NN * 64;
    u16* hT    = (u16*)(ws + HT_OFF);

    k_pre<<<3476, 256, 0, stream>>>(x, input_np, output_np, edge_nt, edge_np, edge_sc,
                                    in_emb, out_emb, ent_emb, enp_emb, w1, b1, w2, b2,
                                    rootw, wsup, wnt, wtg, wpr,
                                    xf, w2t, rootT, wcatT, hT, (float4*)sums);
    k_msg<<<236, 512, 0, stream>>>(edge_idx, xf, hT, w2t, sums, cnt);
    k_out<<<235, 256, 0, stream>>>(xf, sums, cnt, rootT, wcatT, convb, bsup, bnt, btg, bpr, (float*)d_out);
}